// Round 9
// baseline (195.453 us; speedup 1.0000x reference)
//
#include <hip/hip_runtime.h>
#include <hip/hip_bf16.h>

// Problem constants: B=2, T=2048, D=1024, H=16, DK=64
constexpr int Bc = 2;
constexpr int Tc = 2048;
constexpr int Mc = Bc * Tc;  // 4096
constexpr float CfQ = 0.18033688011112042f;  // (1/sqrt(64)) * log2(e)

typedef __attribute__((ext_vector_type(8))) __bf16 bf16x8;
typedef __attribute__((ext_vector_type(4))) __bf16 bf16x4;
typedef __attribute__((ext_vector_type(4))) float floatx4;

__device__ __forceinline__ void gl_lds16(const void* g, void* l) {
    __builtin_amdgcn_global_load_lds(
        (const __attribute__((address_space(1))) void*)g,
        (__attribute__((address_space(3))) void*)l, 16, 0, 0);
}

// ---------------------------------------------------------------------------
// Prep: z<4 -> weight transpose+convert; z>=4 -> x fp32->bf16 convert slices.
// ---------------------------------------------------------------------------
__global__ __launch_bounds__(256) void prep_all(const float* __restrict__ x,
                                                const float* __restrict__ Wq,
                                                const float* __restrict__ Wk,
                                                const float* __restrict__ Wv,
                                                const float* __restrict__ Wo,
                                                __bf16* __restrict__ xb,
                                                __bf16* __restrict__ Wqkv,
                                                __bf16* __restrict__ Wot) {
    const int z = blockIdx.z;
    const int tid = threadIdx.x;
    if (z >= 4) {
        const int lb = blockIdx.y * 16 + blockIdx.x;
        const size_t base = ((size_t)(z - 4) * 256 + lb) * 4096;
#pragma unroll
        for (int it = 0; it < 4; ++it) {
            const size_t i = base + (size_t)(it * 256 + tid) * 4;
            const float4 v = *(const float4*)(x + i);
            bf16x4 r;
            r[0] = (__bf16)v.x; r[1] = (__bf16)v.y;
            r[2] = (__bf16)v.z; r[3] = (__bf16)v.w;
            *(bf16x4*)(xb + i) = r;
        }
        return;
    }
    __shared__ float t[64][65];
    const float* W = (z == 0) ? Wq : (z == 1) ? Wk : (z == 2) ? Wv : Wo;
    __bf16* Wt = (z < 3) ? Wqkv + (size_t)z * 1024 * 1024 : Wot;
    const int k0 = blockIdx.y * 64, n0 = blockIdx.x * 64;
    const int c = tid & 63, r0 = tid >> 6;
#pragma unroll
    for (int i = 0; i < 16; ++i)
        t[r0 + i * 4][c] = W[(size_t)(k0 + r0 + i * 4) * 1024 + n0 + c];
    __syncthreads();
#pragma unroll
    for (int i = 0; i < 16; ++i) {
        const int r = r0 + i * 4;
        Wt[(size_t)(n0 + r) * 1024 + k0 + c] = (__bf16)t[c][r];
    }
}

// ---------------------------------------------------------------------------
// bf16 MFMA GEMM, BK=64 (32 MFMA per barrier): C = A @ Bt^T + bias.
// 128xTN tile, 256 threads = 4 waves. XOR-swizzled LDS chunks.
// FUSE_VT (QKV gemm): cols <1024 (Q) pre-scaled by CfQ; cols >=2048 (V)
// stream into permuted Vp[bh][d][t' within 64-tiles].
// ---------------------------------------------------------------------------
template <int TN, bool BF16_OUT, bool FUSE_VT>
__global__ __launch_bounds__(256) void gemm_bt(const __bf16* __restrict__ A,
                                               const __bf16* __restrict__ Bt,
                                               const float* __restrict__ b0,
                                               const float* __restrict__ b1,
                                               const float* __restrict__ b2,
                                               void* __restrict__ Cv,
                                               __bf16* __restrict__ Vt,
                                               int K, int ldc) {
    constexpr int NI = TN / 32;
    __shared__ __bf16 As[128 * 64];
    __shared__ __bf16 Bs[TN * 64];
    const int tid = threadIdx.x, lane = tid & 63, wave = tid >> 6;
    const int wm = wave & 1, wn = wave >> 1;
    const int bm = blockIdx.y * 128, bn = blockIdx.x * TN;
    const __bf16* Ab = A + (size_t)bm * K;
    const __bf16* Bb = Bt + (size_t)bn * K;
    const int quad = lane >> 4, tm = lane & 15;
    const int tsw = tm & 7;

    floatx4 acc[4][NI] = {};

    for (int k0 = 0; k0 < K; k0 += 64) {
#pragma unroll
        for (int i = 0; i < 4; ++i) {
            const int s = i * 256 + tid;
            const int row = s >> 3;
            const int lc = (s & 7) ^ (row & 7);
            gl_lds16(Ab + (size_t)row * K + k0 + lc * 8, As + s * 8);
        }
#pragma unroll
        for (int i = 0; i < TN / 32; ++i) {
            const int s = i * 256 + tid;
            const int row = s >> 3;
            const int lc = (s & 7) ^ (row & 7);
            gl_lds16(Bb + (size_t)row * K + k0 + lc * 8, Bs + s * 8);
        }
        __syncthreads();
        bf16x8 af[4][2], bfv[NI][2];
#pragma unroll
        for (int mi = 0; mi < 4; ++mi) {
            const int row = (wm * 64 + mi * 16 + tm) * 64;
#pragma unroll
            for (int ks = 0; ks < 2; ++ks)
                af[mi][ks] = *(const bf16x8*)(As + row + ((ks * 4 + quad) ^ tsw) * 8);
        }
#pragma unroll
        for (int ni = 0; ni < NI; ++ni) {
            const int row = (wn * (TN / 2) + ni * 16 + tm) * 64;
#pragma unroll
            for (int ks = 0; ks < 2; ++ks)
                bfv[ni][ks] = *(const bf16x8*)(Bs + row + ((ks * 4 + quad) ^ tsw) * 8);
        }
#pragma unroll
        for (int ks = 0; ks < 2; ++ks)
#pragma unroll
            for (int mi = 0; mi < 4; ++mi)
#pragma unroll
                for (int ni = 0; ni < NI; ++ni)
                    acc[mi][ni] = __builtin_amdgcn_mfma_f32_16x16x32_bf16(
                        af[mi][ks], bfv[ni][ks], acc[mi][ni], 0, 0, 0);
        __syncthreads();
    }

#pragma unroll
    for (int ni = 0; ni < NI; ++ni) {
        const int gc = bn + wn * (TN / 2) + ni * 16 + tm;
        const float bias = (gc < 1024) ? b0[gc]
                         : (gc < 2048) ? b1[gc - 1024]
                                       : b2[gc - 2048];
        const float scale = (FUSE_VT && gc < 1024) ? CfQ : 1.0f;
#pragma unroll
        for (int mi = 0; mi < 4; ++mi) {
            const int gr0 = bm + wm * 64 + mi * 16 + quad * 4;
            if (FUSE_VT && gc >= 2048) {
                bf16x4 pv;
#pragma unroll
                for (int r = 0; r < 4; ++r) pv[r] = (__bf16)(acc[mi][ni][r] + bias);
                const int bb = gr0 >> 11, tloc = gr0 & 2047;
                const int hh = (gc - 2048) >> 6, dd = gc & 63;
                const int tperm = (tloc & ~63) + ((tloc >> 2) & 3) * 16 +
                                  ((tloc >> 4) & 3) * 4;
                *(bf16x4*)(Vt + ((size_t)(bb * 16 + hh) * 64 + dd) * 2048 + tperm) = pv;
            } else if (BF16_OUT) {
#pragma unroll
                for (int r = 0; r < 4; ++r)
                    ((__bf16*)Cv)[(size_t)(gr0 + r) * ldc + gc] =
                        (__bf16)((acc[mi][ni][r] + bias) * scale);
            } else {
#pragma unroll
                for (int r = 0; r < 4; ++r)
                    ((float*)Cv)[(size_t)(gr0 + r) * ldc + gc] =
                        acc[mi][ni][r] + bias;
            }
        }
    }
}

// ---------------------------------------------------------------------------
// MFMA flash attention (causal), S^T formulation, fixed-reference softmax,
// K-SPLIT heavy tiles. Grid (48, B*H):
//   x<32:  qt = 31-(x>>1) (>=16), half = x&1: half0 kt 0..15 (16 visits),
//          half1 kt 16..qt (qt-15 visits). Emit unnormalized O^T (bf16) + l.
//   x>=32: qt = 47-x (<16), full kt 0..qt, normalize + write ctx directly.
// Fixed-m softmax => partials are purely additive; combine = (O0+O1)/(l0+l1).
// Critical path 32 -> 16 visits; 1536 blocks, heavy-first, 5 blocks/CU.
// ---------------------------------------------------------------------------
__global__ __launch_bounds__(256) void attn_mfma(const __bf16* __restrict__ QK,
                                                 const __bf16* __restrict__ Vt,
                                                 __bf16* __restrict__ ctx,
                                                 __bf16* __restrict__ Opart,
                                                 float* __restrict__ Lpart) {
    constexpr float NEG = -1e30f;

    __shared__ __bf16 Ks[2][64 * 64];
    __shared__ __bf16 Vts[2][64 * 64];

    const int tid = threadIdx.x, lane = tid & 63, w = tid >> 6;
    const int c = lane & 15, quad = lane >> 4;
    const int bh = blockIdx.y, b = bh >> 4, h = bh & 15;
    const int x = blockIdx.x;

    int qt, kt0, nv, half;
    bool split;
    if (x < 32) {
        qt = 31 - (x >> 1);
        half = x & 1;
        split = true;
        if (half == 0) { kt0 = 0; nv = 16; }
        else           { kt0 = 16; nv = qt - 15; }
    } else {
        qt = 47 - x;
        half = 0;
        split = false;
        kt0 = 0;
        nv = qt + 1;
    }
    const bool has_diag = (kt0 + nv - 1 == qt);

    const __bf16* Qb = QK + (size_t)(b * Tc) * 2048 + h * 64;
    const __bf16* Kb = Qb + 1024;
    const __bf16* Vtb = Vt + (size_t)bh * 64 * 2048;

    // Q fragments (B-operand: n = q-row = lane&15)
    const __bf16* qr = Qb + (size_t)(qt * 64 + w * 16 + c) * 2048;
    const bf16x8 qf0 = *(const bf16x8*)(qr + quad * 8);
    const bf16x8 qf1 = *(const bf16x8*)(qr + 32 + quad * 8);

    float lsum = 0.f;
    floatx4 oa[4] = {};

    // --- hoisted frag LDS offsets (sw = c&7 loop-invariant) ---
    const int sw = c & 7;
    int koff0[4], koff1[4];
#pragma unroll
    for (int ni = 0; ni < 4; ++ni) {
        const int krow = ni * 16 + c;
        koff0[ni] = krow * 64 + (quad ^ sw) * 8;
        koff1[ni] = krow * 64 + ((4 + quad) ^ sw) * 8;
    }
    int voff[4][2];
#pragma unroll
    for (int di = 0; di < 4; ++di) {
        const int vrow = di * 16 + c;
#pragma unroll
        for (int pr = 0; pr < 2; ++pr)
            voff[di][pr] = vrow * 64 + ((quad * 2 + pr) ^ sw) * 8;
    }

    // --- staging pointers (swizzled 16B chunks), starting at k-tile kt0 ---
    const int srow = tid >> 3;
    const int slc = (tid & 7) ^ (srow & 7);
    const __bf16* kg0 = Kb + (size_t)(kt0 * 64 + srow) * 2048 + slc * 8;
    const __bf16* kg1 = kg0 + (size_t)32 * 2048;
    const __bf16* vg0 = Vtb + (size_t)srow * 2048 + kt0 * 64 + slc * 8;
    const __bf16* vg1 = vg0 + (size_t)32 * 2048;

    gl_lds16(kg0, &Ks[0][tid * 8]);
    gl_lds16(kg1, &Ks[0][tid * 8 + 2048]);
    gl_lds16(vg0, &Vts[0][tid * 8]);
    gl_lds16(vg1, &Vts[0][tid * 8 + 2048]);
    kg0 += (size_t)64 * 2048; kg1 += (size_t)64 * 2048;
    vg0 += 64; vg1 += 64;
    __syncthreads();

    for (int iv = 0; iv < nv; ++iv) {
        const int buf = iv & 1;
        if (iv + 1 < nv) {
            __bf16* kd = &Ks[buf ^ 1][tid * 8];
            __bf16* vd = &Vts[buf ^ 1][tid * 8];
            gl_lds16(kg0, kd);
            gl_lds16(kg1, kd + 2048);
            gl_lds16(vg0, vd);
            gl_lds16(vg1, vd + 2048);
            kg0 += (size_t)64 * 2048; kg1 += (size_t)64 * 2048;
            vg0 += 64; vg1 += 64;
        }
        const __bf16* ks = Ks[buf];
        const __bf16* vs = Vts[buf];

        // --- S^T = K.Q^T : sv[ni][r] = S[k=16ni+quad*4+r][q=c] (pre-scaled) ---
        float sv[4][4];
#pragma unroll
        for (int ni = 0; ni < 4; ++ni) {
            const bf16x8 kb0 = *(const bf16x8*)(ks + koff0[ni]);
            const bf16x8 kb1 = *(const bf16x8*)(ks + koff1[ni]);
            floatx4 a = {};
            a = __builtin_amdgcn_mfma_f32_16x16x32_bf16(kb0, qf0, a, 0, 0, 0);
            a = __builtin_amdgcn_mfma_f32_16x16x32_bf16(kb1, qf1, a, 0, 0, 0);
#pragma unroll
            for (int r = 0; r < 4; ++r) sv[ni][r] = a[r];
        }

        // --- fixed-m softmax: p = exp2(s); per-lane partial l ---
        if (has_diag && iv == nv - 1) {  // diagonal: mask k_loc > q_loc
#pragma unroll
            for (int ni = 0; ni < 4; ++ni)
#pragma unroll
                for (int r = 0; r < 4; ++r)
                    if (ni * 16 + quad * 4 + r > w * 16 + c) sv[ni][r] = NEG;
        }
#pragma unroll
        for (int ni = 0; ni < 4; ++ni)
#pragma unroll
            for (int r = 0; r < 4; ++r) {
                const float p = __builtin_exp2f(sv[ni][r]);
                sv[ni][r] = p;
                lsum += p;
            }

        // pack P into B-frags
        bf16x8 pb[2];
#pragma unroll
        for (int pr = 0; pr < 2; ++pr)
#pragma unroll
            for (int j = 0; j < 4; ++j) {
                pb[pr][j] = (__bf16)sv[pr * 2][j];
                pb[pr][4 + j] = (__bf16)sv[pr * 2 + 1][j];
            }

        // --- O^T += V^T.P^T (Vp layout: frag = single b128 read) ---
#pragma unroll
        for (int di = 0; di < 4; ++di) {
#pragma unroll
            for (int pr = 0; pr < 2; ++pr) {
                const bf16x8 vf = *(const bf16x8*)(vs + voff[di][pr]);
                oa[di] = __builtin_amdgcn_mfma_f32_16x16x32_bf16(
                    vf, pb[pr], oa[di], 0, 0, 0);
            }
        }
        __syncthreads();
    }

    // --- l reduction (once) ---
    lsum += __shfl_xor(lsum, 16);
    lsum += __shfl_xor(lsum, 32);

    if (split) {
        // unnormalized partial: O^T bf16 [q][d] + l
        const size_t pbase = ((size_t)(bh * 16 + (qt - 16)) * 2 + half);
        if (quad == 0) Lpart[pbase * 64 + w * 16 + c] = lsum;
        __bf16* Op = Opart + pbase * 4096 + (size_t)(w * 16 + c) * 64;
#pragma unroll
        for (int di = 0; di < 4; ++di) {
            bf16x4 rv;
#pragma unroll
            for (int r = 0; r < 4; ++r) rv[r] = (__bf16)oa[di][r];
            *(bf16x4*)(Op + di * 16 + quad * 4) = rv;
        }
    } else {
        const float inv = 1.f / lsum;
        __bf16* cp = ctx + (size_t)(b * Tc + qt * 64 + w * 16 + c) * 1024 +
                     h * 64 + quad * 4;
#pragma unroll
        for (int di = 0; di < 4; ++di) {
            bf16x4 rv;
#pragma unroll
            for (int r = 0; r < 4; ++r) rv[r] = (__bf16)(oa[di][r] * inv);
            *(bf16x4*)(cp + di * 16) = rv;
        }
    }
}

// ---------------------------------------------------------------------------
// Combine split tiles: ctx = (O0+O1)/(l0+l1). Grid (16 qt16, 32 bh).
// Thread -> q = tid>>2, d-slice (tid&3)*16.
// ---------------------------------------------------------------------------
__global__ __launch_bounds__(256) void attn_combine(const __bf16* __restrict__ Opart,
                                                    const float* __restrict__ Lpart,
                                                    __bf16* __restrict__ ctx) {
    const int tid = threadIdx.x;
    const int q16 = blockIdx.x, bh = blockIdx.y;
    const int b = bh >> 4, h = bh & 15;
    const int qt = q16 + 16;
    const int q = tid >> 2, ds = (tid & 3) * 16;
    const size_t pb0 = (size_t)(bh * 16 + q16) * 2;
    const size_t pb1 = pb0 + 1;

    const float l = Lpart[pb0 * 64 + q] + Lpart[pb1 * 64 + q];
    const float inv = 1.f / l;

    const __bf16* O0 = Opart + pb0 * 4096 + (size_t)q * 64 + ds;
    const __bf16* O1 = Opart + pb1 * 4096 + (size_t)q * 64 + ds;
    __bf16* cp = ctx + (size_t)(b * Tc + qt * 64 + q) * 1024 + h * 64 + ds;
#pragma unroll
    for (int u = 0; u < 2; ++u) {
        const bf16x8 a = *(const bf16x8*)(O0 + u * 8);
        const bf16x8 bb = *(const bf16x8*)(O1 + u * 8);
        bf16x8 o;
#pragma unroll
        for (int j = 0; j < 8; ++j)
            o[j] = (__bf16)(((float)a[j] + (float)bb[j]) * inv);
        *(bf16x8*)(cp + u * 8) = o;
    }
}

// ---------------------------------------------------------------------------
// kernel_launch. Workspace (bf16 el): xb/ctxb (aliased) 4M | Wqkv 3M |
// Wot 1M | QKb 8M | Vt 4M | Opart 4M | Lpart 64K fp32  ~= 48.3 MB.
// ---------------------------------------------------------------------------
extern "C" void kernel_launch(void* const* d_in, const int* in_sizes, int n_in,
                              void* d_out, int out_size, void* d_ws, size_t ws_size,
                              hipStream_t stream) {
    const float* x  = (const float*)d_in[0];
    const float* Wq = (const float*)d_in[1];
    const float* bq = (const float*)d_in[2];
    const float* Wk = (const float*)d_in[3];
    const float* bk = (const float*)d_in[4];
    const float* Wv = (const float*)d_in[5];
    const float* bv = (const float*)d_in[6];
    const float* Wo = (const float*)d_in[7];
    const float* bo = (const float*)d_in[8];

    __bf16* xb    = (__bf16*)d_ws;                   // [4096][1024]
    __bf16* Wqkv  = xb + (size_t)Mc * 1024;          // [3072][1024] (B^T)
    __bf16* Wot   = Wqkv + (size_t)3072 * 1024;      // [1024][1024] (B^T)
    __bf16* QKb   = Wot + (size_t)1024 * 1024;       // [4096][2048]  Q|K
    __bf16* Vtw   = QKb + (size_t)Mc * 2048;         // [32][64][2048] (permuted)
    __bf16* Opart = Vtw + (size_t)32 * 64 * 2048;    // [32*16*2][64][64]
    float*  Lpart = (float*)(Opart + (size_t)32 * 16 * 2 * 4096);  // [32*16*2][64]
    __bf16* ctxb  = xb;                              // alias: xb dead after QKV GEMM

    prep_all<<<dim3(16, 16, 8), 256, 0, stream>>>(x, Wq, Wk, Wv, Wo,
                                                  xb, Wqkv, Wot);

    // QKV projection: N=3072; Q pre-scaled; V streams permuted into Vtw
    gemm_bt<128, true, true><<<dim3(24, 32), 256, 0, stream>>>(
        xb, Wqkv, bq, bk, bv, QKb, Vtw, 1024, 2048);

    attn_mfma<<<dim3(48, 32), 256, 0, stream>>>(QKb, Vtw, ctxb, Opart, Lpart);
    attn_combine<<<dim3(16, 32), 256, 0, stream>>>(Opart, Lpart, ctxb);

    // Output projection: N=1024, fp32 out
    gemm_bt<64, false, false><<<dim3(16, 32), 256, 0, stream>>>(
        ctxb, Wot, bo, bo, bo, d_out, nullptr, 1024, 1024);
}